// Round 11
// baseline (593.001 us; speedup 1.0000x reference)
//
#include <hip/hip_runtime.h>
#include <math.h>

#define IN_DIM 16
#define HDIM   128
#define HEADS  4
#define HH     512   // HEADS*HDIM
#define FFH    256   // 2*HDIM
#define NEG_SLOPE 0.2f

typedef _Float16 half8 __attribute__((ext_vector_type(8)));
typedef _Float16 h8 __attribute__((ext_vector_type(8)));
typedef _Float16 h4 __attribute__((ext_vector_type(4)));
typedef _Float16 h2 __attribute__((ext_vector_type(2)));
typedef float f32x4 __attribute__((ext_vector_type(4)));

struct __align__(8) Edge { int src; _Float16 ea0, ea1; };

static __device__ inline float hsum8(h8 v) {
    h4 a = __builtin_shufflevector(v, v, 0, 1, 2, 3) +
           __builtin_shufflevector(v, v, 4, 5, 6, 7);
    h2 b = __builtin_shufflevector(a, a, 0, 1) +
           __builtin_shufflevector(a, a, 2, 3);
    return (float)b[0] + (float)b[1];
}

// ---------------------------------------------------------------------------
// Weight convert (+transpose +K-pad) AND x-pad, one kernel.
// m==0: W[Ksrc][N] fp32 -> WT[N][Kd] f16 (zero pad).
// m>0 : xpad: dst[r][64] = f16(src[r][Ksrc]) zero-padded, r in [0,m).
// ---------------------------------------------------------------------------
struct WDesc { const float* src; _Float16* dst; int Ksrc; int lgKd; int lgN; int m; };
struct WDescs { WDesc d[16]; };
__global__ void wconv_kernel(WDescs ds) {
    WDesc w = ds.d[blockIdx.y];
    if (w.m > 0) {
        int total = w.m << 6;
        for (int idx = blockIdx.x * 256 + threadIdx.x; idx < total; idx += gridDim.x * 256) {
            int r = idx >> 6, k = idx & 63;
            w.dst[idx] = (k < w.Ksrc) ? (_Float16)w.src[r * w.Ksrc + k] : (_Float16)0.0f;
        }
    } else {
        int Kd = 1 << w.lgKd;
        int total = 1 << (w.lgKd + w.lgN);
        for (int idx = blockIdx.x * 256 + threadIdx.x; idx < total; idx += gridDim.x * 256) {
            int n2 = idx >> w.lgKd, k = idx & (Kd - 1);
            w.dst[idx] = (k < w.Ksrc) ? (_Float16)w.src[(k << w.lgN) + n2] : (_Float16)0.0f;
        }
    }
}

// ---------------------------------------------------------------------------
// Preprocess: degree + edge_attr sums (self-loop fill_value='mean')
// ---------------------------------------------------------------------------
__global__ void deg_kernel(const int* __restrict__ ei, const float* __restrict__ eattr,
                           float* deg, float* asum, int E) {
    int e = blockIdx.x * blockDim.x + threadIdx.x;
    if (e >= E) return;
    int d = ei[E + e];
    atomicAdd(&deg[d], 1.0f);
    atomicAdd(&asum[2 * d], eattr[2 * e]);
    atomicAdd(&asum[2 * d + 1], eattr[2 * e + 1]);
}

__global__ void scan_kernel(const float* __restrict__ deg, int* row_ptr, int* cur, int n) {
    __shared__ int sums[1024];
    int tid = threadIdx.x;
    int per = (n + 1023) / 1024;
    int s0 = tid * per;
    int s1 = s0 + per; if (s1 > n) s1 = n;
    int s = 0;
    for (int i = s0; i < s1; i++) s += (int)deg[i] + 1;
    int mysum = s;
    sums[tid] = s;
    __syncthreads();
    for (int dd = 1; dd < 1024; dd <<= 1) {
        int t = (tid >= dd) ? sums[tid - dd] : 0;
        __syncthreads();
        sums[tid] += t;
        __syncthreads();
    }
    int run = sums[tid] - mysum;   // exclusive prefix
    for (int i = s0; i < s1; i++) {
        row_ptr[i] = run; cur[i] = run;
        run += (int)deg[i] + 1;
    }
    if (tid == 1023) row_ptr[n] = sums[1023];
}

__global__ void scatter_kernel(const int* __restrict__ ei, const float* __restrict__ eattr,
                               const float* __restrict__ deg, const float* __restrict__ asum,
                               int* cur, Edge* csr, int E, int n) {
    int i = blockIdx.x * blockDim.x + threadIdx.x;
    if (i >= E + n) return;
    Edge ed;
    int pos;
    if (i < E) {
        int d = ei[E + i];
        pos = atomicAdd(&cur[d], 1);
        ed.src = ei[i];
        ed.ea0 = (_Float16)eattr[2 * i];
        ed.ea1 = (_Float16)eattr[2 * i + 1];
    } else {
        int nd = i - E;
        float dv = fmaxf(deg[nd], 1.0f);
        pos = atomicAdd(&cur[nd], 1);
        ed.src = nd;
        ed.ea0 = (_Float16)(asum[2 * nd] / dv);
        ed.ea1 = (_Float16)(asum[2 * nd + 1] / dv);
    }
    csr[pos] = ed;
}

// ---------------------------------------------------------------------------
// B-stationary MFMA GEMM for K<=128: BT staged once, B-frags in registers,
// barrier-free grid-stride M loop, A direct from global. f16 out.
// ---------------------------------------------------------------------------
template <int KT>
__global__ __launch_bounds__(256) void gemm_bstat(const _Float16* __restrict__ A, int lda,
                                                  const _Float16* __restrict__ BT,
                                                  const float* __restrict__ bias,
                                                  _Float16* __restrict__ C16,
                                                  int M, int Nstride, int numMT) {
    const int PAD = 8, KC = KT / 32;
    __shared__ _Float16 Bs[128][KT + PAD];
    int tid = threadIdx.x;
    int wave = tid >> 6, lane = tid & 63;
    int quad = lane >> 4, l16 = lane & 15;
    int wrow = (wave >> 1) * 32, wcol = (wave & 1) * 64;
    int n0 = blockIdx.x * 128;

#pragma unroll
    for (int t = 0; t < KT / 16; t++) {
        int idx = tid + t * 256;
        int r = idx / (KT / 8), kb = (idx % (KT / 8)) * 8;
        *(half8*)&Bs[r][kb] = *(const half8*)(BT + (size_t)(n0 + r) * KT + kb);
    }
    __syncthreads();

    half8 bfrag[4][KC];
#pragma unroll
    for (int j = 0; j < 4; j++)
#pragma unroll
        for (int kc = 0; kc < KC; kc++)
            bfrag[j][kc] = *(const half8*)&Bs[wcol + j * 16 + l16][kc * 32 + quad * 8];

    float biasj[4];
#pragma unroll
    for (int j = 0; j < 4; j++)
        biasj[j] = bias ? bias[n0 + wcol + j * 16 + l16] : 0.0f;

    for (int mt = blockIdx.y; mt < numMT; mt += gridDim.y) {
        int rbase = mt * 64 + wrow;
        half8 af[2][KC];
#pragma unroll
        for (int i = 0; i < 2; i++) {
            int row = rbase + i * 16 + l16;
#pragma unroll
            for (int kc = 0; kc < KC; kc++)
                af[i][kc] = (row < M) ? *(const half8*)(A + (size_t)row * lda + kc * 32 + quad * 8)
                                      : (half8)(_Float16)0.0f;
        }
        f32x4 acc[2][4] = {};
#pragma unroll
        for (int kc = 0; kc < KC; kc++)
#pragma unroll
            for (int i = 0; i < 2; i++)
#pragma unroll
                for (int j = 0; j < 4; j++)
                    acc[i][j] = __builtin_amdgcn_mfma_f32_16x16x32_f16(af[i][kc], bfrag[j][kc], acc[i][j], 0, 0, 0);
#pragma unroll
        for (int i = 0; i < 2; i++) {
#pragma unroll
            for (int r = 0; r < 4; r++) {
                int row = rbase + i * 16 + quad * 4 + r;
                if (row >= M) continue;
#pragma unroll
                for (int j = 0; j < 4; j++) {
                    int col = n0 + wcol + j * 16 + l16;
                    C16[(size_t)row * Nstride + col] = (_Float16)(acc[i][j][r] + biasj[j]);
                }
            }
        }
    }
}

// ---------------------------------------------------------------------------
// Fused GEMM(+bias) + f16-residual + LayerNorm, N=128, register LN. f16 out.
// ---------------------------------------------------------------------------
__global__ __launch_bounds__(256) void gemm_ln(const _Float16* __restrict__ A, int lda,
                                               const _Float16* __restrict__ BT,
                                               const float* __restrict__ bias,
                                               const _Float16* __restrict__ R16,
                                               const float* __restrict__ g,
                                               const float* __restrict__ b,
                                               _Float16* __restrict__ C16,
                                               int M, int K) {
    const int BK = 64, PAD = 8;
    __shared__ _Float16 As[64][BK + PAD];
    __shared__ _Float16 Bs[128][BK + PAD];
    int tid = threadIdx.x;
    int wave = tid >> 6, lane = tid & 63;
    int quad = lane >> 4, l16 = lane & 15;
    int mBase = blockIdx.x * 64;

    f32x4 acc[8] = {};

    for (int k0 = 0; k0 < K; k0 += BK) {
#pragma unroll
        for (int t = 0; t < 2; t++) {
            int idx = tid + t * 256;
            int r = idx >> 3, kb = (idx & 7) * 8;
            half8 hv = {};
            int grow = mBase + r;
            if (grow < M) hv = *(const half8*)(A + (size_t)grow * lda + k0 + kb);
            *(half8*)&As[r][kb] = hv;
        }
#pragma unroll
        for (int t = 0; t < 4; t++) {
            int idx = tid + t * 256;
            int r = idx >> 3, kb = (idx & 7) * 8;
            *(half8*)&Bs[r][kb] = *(const half8*)(BT + (size_t)r * K + k0 + kb);
        }
        __syncthreads();
#pragma unroll
        for (int kc = 0; kc < 2; kc++) {
            half8 a = *(const half8*)&As[wave * 16 + l16][kc * 32 + quad * 8];
#pragma unroll
            for (int j = 0; j < 8; j++) {
                half8 bb = *(const half8*)&Bs[j * 16 + l16][kc * 32 + quad * 8];
                acc[j] = __builtin_amdgcn_mfma_f32_16x16x32_f16(a, bb, acc[j], 0, 0, 0);
            }
        }
        __syncthreads();
    }

    float gj[8], bj[8], biasj[8];
#pragma unroll
    for (int j = 0; j < 8; j++) {
        int col = j * 16 + l16;
        biasj[j] = bias[col];
        gj[j] = g[col];
        bj[j] = b[col];
    }
    int row0 = mBase + wave * 16 + quad * 4;
    float sum[4] = {}, sq[4] = {};
#pragma unroll
    for (int r = 0; r < 4; r++) {
        int row = row0 + r;
        bool ok = row < M;
        size_t base = (size_t)row * HDIM;
#pragma unroll
        for (int j = 0; j < 8; j++) {
            float v = acc[j][r] + biasj[j] + (ok ? (float)R16[base + j * 16 + l16] : 0.0f);
            acc[j][r] = v;
            sum[r] += v;
            sq[r] += v * v;
        }
    }
#pragma unroll
    for (int r = 0; r < 4; r++) {
#pragma unroll
        for (int off = 1; off < 16; off <<= 1) {
            sum[r] += __shfl_xor(sum[r], off);
            sq[r] += __shfl_xor(sq[r], off);
        }
    }
#pragma unroll
    for (int r = 0; r < 4; r++) {
        int row = row0 + r;
        if (row >= M) continue;
        size_t base = (size_t)row * HDIM;
        float mu = sum[r] * (1.0f / HDIM);
        float var = sq[r] * (1.0f / HDIM) - mu * mu;
        float invstd = rsqrtf(var + 1e-5f);
#pragma unroll
        for (int j = 0; j < 8; j++)
            C16[base + j * 16 + l16] = (_Float16)((acc[j][r] - mu) * invstd * gj[j] + bj[j]);
    }
}

// ---------------------------------------------------------------------------
// Fused FFN: LN(GELU(A@W1T + b1)@W2T + b2 + R16) * g + b.
// Output: C32 (final layer, f32) or C16 (f16).
// ---------------------------------------------------------------------------
__global__ __launch_bounds__(256) void ffn_fused(const _Float16* __restrict__ A,
                                                 const _Float16* __restrict__ W1T,
                                                 const float* __restrict__ b1,
                                                 const _Float16* __restrict__ W2T,
                                                 const float* __restrict__ b2,
                                                 const _Float16* __restrict__ R16,
                                                 const float* __restrict__ g,
                                                 const float* __restrict__ b,
                                                 float* __restrict__ C32,
                                                 _Float16* __restrict__ C16,
                                                 int M) {
    __shared__ _Float16 Ws[128][128 + 8];
    __shared__ _Float16 Mid[64][256 + 8];
    int tid = threadIdx.x;
    int wave = tid >> 6, lane = tid & 63;
    int quad = lane >> 4, l16 = lane & 15;
    int mBase = blockIdx.x * 64;

    half8 afrag[4];
    {
        int row = mBase + wave * 16 + l16;
#pragma unroll
        for (int kc = 0; kc < 4; kc++) {
            if (row < M)
                afrag[kc] = *(const half8*)(A + (size_t)row * HDIM + kc * 32 + quad * 8);
            else
                afrag[kc] = (half8)(_Float16)0.0f;
        }
    }

#pragma unroll
    for (int h = 0; h < 2; h++) {
        if (h) __syncthreads();
#pragma unroll
        for (int t = 0; t < 8; t++) {
            int idx = tid + t * 256;
            int r = idx >> 4, kb = (idx & 15) * 8;
            *(half8*)&Ws[r][kb] = *(const half8*)(W1T + (size_t)(h * 128 + r) * HDIM + kb);
        }
        __syncthreads();
        f32x4 acc[8] = {};
#pragma unroll
        for (int kc = 0; kc < 4; kc++) {
#pragma unroll
            for (int j = 0; j < 8; j++) {
                half8 bb = *(const half8*)&Ws[j * 16 + l16][kc * 32 + quad * 8];
                acc[j] = __builtin_amdgcn_mfma_f32_16x16x32_f16(afrag[kc], bb, acc[j], 0, 0, 0);
            }
        }
#pragma unroll
        for (int j = 0; j < 8; j++) {
            float bj1 = b1[h * 128 + j * 16 + l16];
#pragma unroll
            for (int r = 0; r < 4; r++) {
                float v = acc[j][r] + bj1;
                v = 0.5f * v * (1.0f + erff(v * 0.70710678118654752f));
                Mid[wave * 16 + quad * 4 + r][h * 128 + j * 16 + l16] = (_Float16)v;
            }
        }
    }
    __syncthreads();

    f32x4 acc2[8] = {};
#pragma unroll
    for (int kc2 = 0; kc2 < 2; kc2++) {
        if (kc2) __syncthreads();
#pragma unroll
        for (int t = 0; t < 8; t++) {
            int idx = tid + t * 256;
            int r = idx >> 4, kb = (idx & 15) * 8;
            *(half8*)&Ws[r][kb] = *(const half8*)(W2T + (size_t)r * FFH + kc2 * 128 + kb);
        }
        __syncthreads();
#pragma unroll
        for (int kc = 0; kc < 4; kc++) {
            half8 am = *(const half8*)&Mid[wave * 16 + l16][kc2 * 128 + kc * 32 + quad * 8];
#pragma unroll
            for (int j = 0; j < 8; j++) {
                half8 bb = *(const half8*)&Ws[j * 16 + l16][kc * 32 + quad * 8];
                acc2[j] = __builtin_amdgcn_mfma_f32_16x16x32_f16(am, bb, acc2[j], 0, 0, 0);
            }
        }
    }

    float gj[8], bj[8], b2j[8];
#pragma unroll
    for (int j = 0; j < 8; j++) {
        int col = j * 16 + l16;
        b2j[j] = b2[col];
        gj[j] = g[col];
        bj[j] = b[col];
    }
    int row0 = mBase + wave * 16 + quad * 4;
    float sum[4] = {}, sq[4] = {};
#pragma unroll
    for (int r = 0; r < 4; r++) {
        int row = row0 + r;
        bool ok = row < M;
        size_t base = (size_t)row * HDIM;
#pragma unroll
        for (int j = 0; j < 8; j++) {
            float v = acc2[j][r] + b2j[j] + (ok ? (float)R16[base + j * 16 + l16] : 0.0f);
            acc2[j][r] = v;
            sum[r] += v;
            sq[r] += v * v;
        }
    }
#pragma unroll
    for (int r = 0; r < 4; r++) {
#pragma unroll
        for (int off = 1; off < 16; off <<= 1) {
            sum[r] += __shfl_xor(sum[r], off);
            sq[r] += __shfl_xor(sq[r], off);
        }
    }
#pragma unroll
    for (int r = 0; r < 4; r++) {
        int row = row0 + r;
        if (row >= M) continue;
        size_t base = (size_t)row * HDIM;
        float mu = sum[r] * (1.0f / HDIM);
        float var = sq[r] * (1.0f / HDIM) - mu * mu;
        float invstd = rsqrtf(var + 1e-5f);
#pragma unroll
        for (int j = 0; j < 8; j++) {
            float o = (acc2[j][r] - mu) * invstd * gj[j] + bj[j];
            if (C32) C32[base + j * 16 + l16] = o;
            else     C16[base + j * 16 + l16] = (_Float16)o;
        }
    }
}

// ---------------------------------------------------------------------------
// GATv2 attention + aggregation, packed-f16 math, one wave per dst node,
// online softmax, 2-edge unroll. XLR: [n][1024] f16 (XL 0..511, XR 512..1023).
// Concat: f16 into XR half. Non-concat: head-mean + bias + f16-residual + LN
// fused, f16 out.
// ---------------------------------------------------------------------------
__global__ __launch_bounds__(256) void gat_edge_kernel(
    const _Float16* __restrict__ XLR,
    const int* __restrict__ row_ptr, const Edge* __restrict__ csr,
    const float* __restrict__ We,    // [2,512]
    const float* __restrict__ attW,  // [512]
    const float* __restrict__ cbias, // [512] or [128]
    _Float16* __restrict__ OUT16,
    const _Float16* __restrict__ R16, const float* __restrict__ lng,
    const float* __restrict__ lnb, _Float16* __restrict__ OUT16h,
    int n, int concat) {
    int tid = threadIdx.x;
    int wave = tid >> 6, lane = tid & 63;
    int node = blockIdx.x * 4 + wave;
    if (node >= n) return;
    int c0 = lane * 8;

    h8 xr8 = *(const h8*)(XLR + (size_t)node * 1024 + 512 + c0);
    h8 w08, w18, att8;
#pragma unroll
    for (int k = 0; k < 8; k++) {
        w08[k] = (_Float16)We[c0 + k];
        w18[k] = (_Float16)We[HH + c0 + k];
        att8[k] = (_Float16)attW[c0 + k];
    }
    const _Float16 slope = (_Float16)NEG_SLOPE;

    h8 acc2 = (h8)(_Float16)0.0f;
    float m = -INFINITY, l = 0.0f;
    int beg = row_ptr[node], end = row_ptr[node + 1];
    int j = beg;
    for (; j + 1 < end; j += 2) {
        Edge e0 = csr[j], e1 = csr[j + 1];
        h8 x0 = *(const h8*)(XLR + (size_t)e0.src * 1024 + c0);
        h8 x1 = *(const h8*)(XLR + (size_t)e1.src * 1024 + c0);
        h8 v0 = x0 + (xr8 + w08 * e0.ea0 + w18 * e0.ea1);
        h8 v1 = x1 + (xr8 + w08 * e1.ea0 + w18 * e1.ea1);
        v0 = __builtin_elementwise_max(v0, v0 * slope);
        v1 = __builtin_elementwise_max(v1, v1 * slope);
        float p0 = hsum8(v0 * att8);
        float p1 = hsum8(v1 * att8);
        p0 += __shfl_xor(p0, 1); p1 += __shfl_xor(p1, 1);
        p0 += __shfl_xor(p0, 2); p1 += __shfl_xor(p1, 2);
        p0 += __shfl_xor(p0, 4); p1 += __shfl_xor(p1, 4);
        p0 += __shfl_xor(p0, 8); p1 += __shfl_xor(p1, 8);
        float mnew = fmaxf(m, fmaxf(p0, p1));
        float sc = __expf(m - mnew);
        float e0f = __expf(p0 - mnew);
        float e1f = __expf(p1 - mnew);
        l = l * sc + e0f + e1f;
        acc2 = acc2 * (_Float16)sc + x0 * (_Float16)e0f + x1 * (_Float16)e1f;
        m = mnew;
    }
    if (j < end) {
        Edge e0 = csr[j];
        h8 x0 = *(const h8*)(XLR + (size_t)e0.src * 1024 + c0);
        h8 v0 = x0 + (xr8 + w08 * e0.ea0 + w18 * e0.ea1);
        v0 = __builtin_elementwise_max(v0, v0 * slope);
        float p0 = hsum8(v0 * att8);
        p0 += __shfl_xor(p0, 1);
        p0 += __shfl_xor(p0, 2);
        p0 += __shfl_xor(p0, 4);
        p0 += __shfl_xor(p0, 8);
        float mnew = fmaxf(m, p0);
        float sc = __expf(m - mnew);
        float e0f = __expf(p0 - mnew);
        l = l * sc + e0f;
        acc2 = acc2 * (_Float16)sc + x0 * (_Float16)e0f;
        m = mnew;
    }
    float invf = 1.0f / (l + 1e-16f);
    if (concat) {
        h8 o = acc2 * (_Float16)invf;
#pragma unroll
        for (int k = 0; k < 8; k++) o[k] = o[k] + (_Float16)cbias[c0 + k];
        *(h8*)(OUT16 + (size_t)node * 1024 + c0) = o;
    } else {
        float o8[8];
#pragma unroll
        for (int k = 0; k < 8; k++) {
            float a = (float)acc2[k] * invf;
            a += __shfl_xor(a, 16);
            a += __shfl_xor(a, 32);
            o8[k] = a;
        }
        float v8[8];
        float sum = 0.0f, sq = 0.0f;
        if (lane < 16) {
#pragma unroll
            for (int k = 0; k < 8; k++) {
                float v = o8[k] * 0.25f + cbias[c0 + k] + (float)R16[(size_t)node * HDIM + c0 + k];
                v8[k] = v;
                sum += v;
                sq += v * v;
            }
        }
#pragma unroll
        for (int off = 1; off < 16; off <<= 1) {
            sum += __shfl_xor(sum, off);
            sq += __shfl_xor(sq, off);
        }
        if (lane < 16) {
            float mu = sum * (1.0f / HDIM);
            float var = sq * (1.0f / HDIM) - mu * mu;
            float invstd = rsqrtf(var + 1e-5f);
#pragma unroll
            for (int k = 0; k < 8; k++)
                OUT16h[(size_t)node * HDIM + c0 + k] =
                    (_Float16)((v8[k] - mu) * invstd * lng[c0 + k] + lnb[c0 + k]);
        }
    }
}

// ---------------------------------------------------------------------------
extern "C" void kernel_launch(void* const* d_in, const int* in_sizes, int n_in,
                              void* d_out, int out_size, void* d_ws, size_t ws_size,
                              hipStream_t stream) {
    const float* x        = (const float*)d_in[0];
    const int*   ei       = (const int*)d_in[1];
    const float* eattr    = (const float*)d_in[2];
    const float* emb_w    = (const float*)d_in[3];
    const float* emb_b    = (const float*)d_in[4];
    const float* lin_l    = (const float*)d_in[5];
    const float* lin_r    = (const float*)d_in[6];
    const float* lin_edge = (const float*)d_in[7];
    const float* attw     = (const float*)d_in[8];
    const float* cb01     = (const float*)d_in[9];
    const float* cb2      = (const float*)d_in[10];
    const float* proj_w   = (const float*)d_in[11];
    const float* proj_b   = (const float*)d_in[12];
    const float* n1g      = (const float*)d_in[13];
    const float* n1b      = (const float*)d_in[14];
    const float* n2g      = (const float*)d_in[15];
    const float* n2b      = (const float*)d_in[16];
    const float* fw1      = (const float*)d_in[17];
    const float* fb1      = (const float*)d_in[18];
    const float* fw2      = (const float*)d_in[19];
    const float* fb2      = (const float*)d_in[20];
    float* out = (float*)d_out;

    const int n = in_sizes[0] / IN_DIM;   // 20000
    const int E = in_sizes[2] / 2;        // 320000
    const int EP = E + n;
    const int numMT = (n + 63) / 64;

    size_t off = 0;
    auto alloc = [&](size_t bytes) {
        void* p = (char*)d_ws + off;
        off += (bytes + 255) & ~(size_t)255;
        return p;
    };
    float* degasum = (float*)alloc((size_t)3 * n * 4);  // deg[n] + asum[2n] contiguous
    float* deg     = degasum;
    float* asum    = degasum + n;
    int*   row_ptr = (int*)alloc((size_t)(n + 1) * 4);
    int*   cur     = (int*)alloc((size_t)n * 4);
    Edge*  csr     = (Edge*)alloc((size_t)EP * 8);
    _Float16* H0h  = (_Float16*)alloc((size_t)n * HDIM * 2);
    _Float16* H1h  = (_Float16*)alloc((size_t)n * HDIM * 2);
    _Float16* XLR  = (_Float16*)alloc((size_t)n * 1024 * 2);
    _Float16* xh   = (_Float16*)alloc((size_t)n * 64 * 2);
    _Float16* wt_emb  = (_Float16*)alloc((size_t)HDIM * 64 * 2);
    _Float16* wt_llr  = (_Float16*)alloc((size_t)3 * 1024 * HDIM * 2);
    _Float16* wt_proj = (_Float16*)alloc((size_t)2 * HDIM * HH * 2);
    _Float16* wt_f1   = (_Float16*)alloc((size_t)3 * FFH * HDIM * 2);
    _Float16* wt_f2   = (_Float16*)alloc((size_t)3 * HDIM * FFH * 2);
    (void)ws_size;

    // ---- input prep: 15 weight converts + xpad, one kernel ----
    WDescs ds;
    int di = 0;
    ds.d[di++] = {emb_w, wt_emb, IN_DIM, 6, 7, 0};
    for (int i = 0; i < 3; i++) {
        ds.d[di++] = {lin_l + (size_t)i * HDIM * HH, wt_llr + (size_t)i * 1024 * HDIM, HDIM, 7, 9, 0};
        ds.d[di++] = {lin_r + (size_t)i * HDIM * HH, wt_llr + (size_t)i * 1024 * HDIM + (size_t)512 * HDIM, HDIM, 7, 9, 0};
    }
    for (int i = 0; i < 2; i++)
        ds.d[di++] = {proj_w + (size_t)i * HH * HDIM, wt_proj + (size_t)i * HDIM * HH, HH, 9, 7, 0};
    for (int i = 0; i < 3; i++)
        ds.d[di++] = {fw1 + (size_t)i * HDIM * FFH, wt_f1 + (size_t)i * FFH * HDIM, HDIM, 7, 8, 0};
    for (int i = 0; i < 3; i++)
        ds.d[di++] = {fw2 + (size_t)i * FFH * HDIM, wt_f2 + (size_t)i * HDIM * FFH, FFH, 8, 7, 0};
    ds.d[di++] = {x, xh, IN_DIM, 0, 0, n};   // xpad
    wconv_kernel<<<dim3(64, 16), 256, 0, stream>>>(ds);

    // ---- CSR build ----
    (void)hipMemsetAsync(degasum, 0, (size_t)3 * n * 4, stream);
    deg_kernel<<<(E + 255) / 256, 256, 0, stream>>>(ei, eattr, deg, asum, E);
    scan_kernel<<<1, 1024, 0, stream>>>(deg, row_ptr, cur, n);
    scatter_kernel<<<(EP + 255) / 256, 256, 0, stream>>>(ei, eattr, deg, asum, cur, csr, E, n);

    // ---- Embedding: H0h = xh @ wt_emb + emb_b (B-stationary, f16) ----
    gemm_bstat<64><<<dim3(1, numMT), 256, 0, stream>>>(
        xh, 64, wt_emb, emb_b, H0h, n, HDIM, numMT);

    // ---- 3 GATv2 + FFN layers (all-f16 inter-layer state) ----
    for (int i = 0; i < 3; i++) {
        int concat = (i < 2);
        // fused lin_l|lin_r: XLR[n][1024]
        gemm_bstat<128><<<dim3(8, 80), 256, 0, stream>>>(
            H0h, HDIM, wt_llr + (size_t)i * 1024 * HDIM, nullptr, XLR, n, 1024, numMT);
        // gat: concat -> f16 into XR half; non-concat -> fused mean+bias+res+LN
        gat_edge_kernel<<<(n + 3) / 4, 256, 0, stream>>>(
            XLR, row_ptr, csr,
            lin_edge + (size_t)i * 2 * HH, attw + (size_t)i * HH,
            concat ? (cb01 + (size_t)i * HH) : cb2,
            XLR + 512,
            H0h, n1g + (size_t)i * HDIM, n1b + (size_t)i * HDIM, H1h,
            n, concat);
        if (concat) {
            // H1h = LN(proj(gatout) + pb + H0h)
            gemm_ln<<<(n + 63) / 64, 256, 0, stream>>>(
                XLR + 512, 1024, wt_proj + (size_t)i * HDIM * HH,
                proj_b + (size_t)i * HDIM, H0h,
                n1g + (size_t)i * HDIM, n1b + (size_t)i * HDIM,
                H1h, n, HH);
        }
        // {out|H0h} = LN(GELU(H1h@W1+b1)@W2 + b2 + H1h)
        ffn_fused<<<(n + 63) / 64, 256, 0, stream>>>(
            H1h, wt_f1 + (size_t)i * FFH * HDIM, fb1 + (size_t)i * FFH,
            wt_f2 + (size_t)i * HDIM * FFH, fb2 + (size_t)i * HDIM, H1h,
            n2g + (size_t)i * HDIM, n2b + (size_t)i * HDIM,
            (i == 2) ? out : nullptr, (i == 2) ? nullptr : H0h, n);
    }
}

// Round 12
// 567.345 us; speedup vs baseline: 1.0452x; 1.0452x over previous
//
#include <hip/hip_runtime.h>
#include <math.h>

#define IN_DIM 16
#define HDIM   128
#define HEADS  4
#define HH     512   // HEADS*HDIM
#define FFH    256   // 2*HDIM
#define NEG_SLOPE 0.2f

typedef _Float16 half8 __attribute__((ext_vector_type(8)));
typedef _Float16 h8 __attribute__((ext_vector_type(8)));
typedef _Float16 h4 __attribute__((ext_vector_type(4)));
typedef _Float16 h2 __attribute__((ext_vector_type(2)));
typedef float f32x4 __attribute__((ext_vector_type(4)));

struct __align__(8) Edge { int src; _Float16 ea0, ea1; };

static __device__ inline float hsum8(h8 v) {
    h4 a = __builtin_shufflevector(v, v, 0, 1, 2, 3) +
           __builtin_shufflevector(v, v, 4, 5, 6, 7);
    h2 b = __builtin_shufflevector(a, a, 0, 1) +
           __builtin_shufflevector(a, a, 2, 3);
    return (float)b[0] + (float)b[1];
}

// ---------------------------------------------------------------------------
// x pad: xh[n][64] = f16(x[n][16]) zero-padded. Full grid (one elem/thread).
// ---------------------------------------------------------------------------
__global__ void xpad_kernel(const float* __restrict__ x, _Float16* __restrict__ xh, int n) {
    int idx = blockIdx.x * 256 + threadIdx.x;
    if (idx >= n * 64) return;
    int r = idx >> 6, k = idx & 63;
    xh[idx] = (k < IN_DIM) ? (_Float16)x[r * IN_DIM + k] : (_Float16)0.0f;
}

// ---------------------------------------------------------------------------
// Weight convert+transpose+K-pad: W[Ksrc][N] fp32 -> WT[N][Kd] f16 (zero pad)
// ---------------------------------------------------------------------------
struct WDesc { const float* src; _Float16* dst; int Ksrc; int lgKd; int lgN; };
struct WDescs { WDesc d[15]; };
__global__ void wconv_kernel(WDescs ds) {
    WDesc w = ds.d[blockIdx.y];
    int Kd = 1 << w.lgKd;
    int total = 1 << (w.lgKd + w.lgN);
    for (int idx = blockIdx.x * 256 + threadIdx.x; idx < total; idx += gridDim.x * 256) {
        int n2 = idx >> w.lgKd, k = idx & (Kd - 1);
        w.dst[idx] = (k < w.Ksrc) ? (_Float16)w.src[(k << w.lgN) + n2] : (_Float16)0.0f;
    }
}

// ---------------------------------------------------------------------------
// Preprocess: degree + edge_attr sums (self-loop fill_value='mean')
// ---------------------------------------------------------------------------
__global__ void deg_kernel(const int* __restrict__ ei, const float* __restrict__ eattr,
                           float* deg, float* asum, int E) {
    int e = blockIdx.x * blockDim.x + threadIdx.x;
    if (e >= E) return;
    int d = ei[E + e];
    atomicAdd(&deg[d], 1.0f);
    atomicAdd(&asum[2 * d], eattr[2 * e]);
    atomicAdd(&asum[2 * d + 1], eattr[2 * e + 1]);
}

__global__ void scan_kernel(const float* __restrict__ deg, int* row_ptr, int* cur, int n) {
    __shared__ int sums[1024];
    int tid = threadIdx.x;
    int per = (n + 1023) / 1024;
    int s0 = tid * per;
    int s1 = s0 + per; if (s1 > n) s1 = n;
    int s = 0;
    for (int i = s0; i < s1; i++) s += (int)deg[i] + 1;
    int mysum = s;
    sums[tid] = s;
    __syncthreads();
    for (int dd = 1; dd < 1024; dd <<= 1) {
        int t = (tid >= dd) ? sums[tid - dd] : 0;
        __syncthreads();
        sums[tid] += t;
        __syncthreads();
    }
    int run = sums[tid] - mysum;   // exclusive prefix
    for (int i = s0; i < s1; i++) {
        row_ptr[i] = run; cur[i] = run;
        run += (int)deg[i] + 1;
    }
    if (tid == 1023) row_ptr[n] = sums[1023];
}

__global__ void scatter_kernel(const int* __restrict__ ei, const float* __restrict__ eattr,
                               const float* __restrict__ deg, const float* __restrict__ asum,
                               int* cur, Edge* csr, int E, int n) {
    int i = blockIdx.x * blockDim.x + threadIdx.x;
    if (i >= E + n) return;
    Edge ed;
    int pos;
    if (i < E) {
        int d = ei[E + i];
        pos = atomicAdd(&cur[d], 1);
        ed.src = ei[i];
        ed.ea0 = (_Float16)eattr[2 * i];
        ed.ea1 = (_Float16)eattr[2 * i + 1];
    } else {
        int nd = i - E;
        float dv = fmaxf(deg[nd], 1.0f);
        pos = atomicAdd(&cur[nd], 1);
        ed.src = nd;
        ed.ea0 = (_Float16)(asum[2 * nd] / dv);
        ed.ea1 = (_Float16)(asum[2 * nd + 1] / dv);
    }
    csr[pos] = ed;
}

// ---------------------------------------------------------------------------
// B-stationary MFMA GEMM for K<=128: BT staged once, B-frags in registers,
// barrier-free grid-stride M loop, A direct from global. f16 out.
// ---------------------------------------------------------------------------
template <int KT>
__global__ __launch_bounds__(256) void gemm_bstat(const _Float16* __restrict__ A, int lda,
                                                  const _Float16* __restrict__ BT,
                                                  const float* __restrict__ bias,
                                                  _Float16* __restrict__ C16,
                                                  int M, int Nstride, int numMT) {
    const int PAD = 8, KC = KT / 32;
    __shared__ _Float16 Bs[128][KT + PAD];
    int tid = threadIdx.x;
    int wave = tid >> 6, lane = tid & 63;
    int quad = lane >> 4, l16 = lane & 15;
    int wrow = (wave >> 1) * 32, wcol = (wave & 1) * 64;
    int n0 = blockIdx.x * 128;

#pragma unroll
    for (int t = 0; t < KT / 16; t++) {
        int idx = tid + t * 256;
        int r = idx / (KT / 8), kb = (idx % (KT / 8)) * 8;
        *(half8*)&Bs[r][kb] = *(const half8*)(BT + (size_t)(n0 + r) * KT + kb);
    }
    __syncthreads();

    half8 bfrag[4][KC];
#pragma unroll
    for (int j = 0; j < 4; j++)
#pragma unroll
        for (int kc = 0; kc < KC; kc++)
            bfrag[j][kc] = *(const half8*)&Bs[wcol + j * 16 + l16][kc * 32 + quad * 8];

    float biasj[4];
#pragma unroll
    for (int j = 0; j < 4; j++)
        biasj[j] = bias ? bias[n0 + wcol + j * 16 + l16] : 0.0f;

    for (int mt = blockIdx.y; mt < numMT; mt += gridDim.y) {
        int rbase = mt * 64 + wrow;
        half8 af[2][KC];
#pragma unroll
        for (int i = 0; i < 2; i++) {
            int row = rbase + i * 16 + l16;
#pragma unroll
            for (int kc = 0; kc < KC; kc++)
                af[i][kc] = (row < M) ? *(const half8*)(A + (size_t)row * lda + kc * 32 + quad * 8)
                                      : (half8)(_Float16)0.0f;
        }
        f32x4 acc[2][4] = {};
#pragma unroll
        for (int kc = 0; kc < KC; kc++)
#pragma unroll
            for (int i = 0; i < 2; i++)
#pragma unroll
                for (int j = 0; j < 4; j++)
                    acc[i][j] = __builtin_amdgcn_mfma_f32_16x16x32_f16(af[i][kc], bfrag[j][kc], acc[i][j], 0, 0, 0);
#pragma unroll
        for (int i = 0; i < 2; i++) {
#pragma unroll
            for (int r = 0; r < 4; r++) {
                int row = rbase + i * 16 + quad * 4 + r;
                if (row >= M) continue;
#pragma unroll
                for (int j = 0; j < 4; j++) {
                    int col = n0 + wcol + j * 16 + l16;
                    C16[(size_t)row * Nstride + col] = (_Float16)(acc[i][j][r] + biasj[j]);
                }
            }
        }
    }
}

// ---------------------------------------------------------------------------
// Fused GEMM(+bias) + f16-residual + LayerNorm, N=128, register LN. f16 out.
// ---------------------------------------------------------------------------
__global__ __launch_bounds__(256) void gemm_ln(const _Float16* __restrict__ A, int lda,
                                               const _Float16* __restrict__ BT,
                                               const float* __restrict__ bias,
                                               const _Float16* __restrict__ R16,
                                               const float* __restrict__ g,
                                               const float* __restrict__ b,
                                               _Float16* __restrict__ C16,
                                               int M, int K) {
    const int BK = 64, PAD = 8;
    __shared__ _Float16 As[64][BK + PAD];
    __shared__ _Float16 Bs[128][BK + PAD];
    int tid = threadIdx.x;
    int wave = tid >> 6, lane = tid & 63;
    int quad = lane >> 4, l16 = lane & 15;
    int mBase = blockIdx.x * 64;

    f32x4 acc[8] = {};

    for (int k0 = 0; k0 < K; k0 += BK) {
#pragma unroll
        for (int t = 0; t < 2; t++) {
            int idx = tid + t * 256;
            int r = idx >> 3, kb = (idx & 7) * 8;
            half8 hv = {};
            int grow = mBase + r;
            if (grow < M) hv = *(const half8*)(A + (size_t)grow * lda + k0 + kb);
            *(half8*)&As[r][kb] = hv;
        }
#pragma unroll
        for (int t = 0; t < 4; t++) {
            int idx = tid + t * 256;
            int r = idx >> 3, kb = (idx & 7) * 8;
            *(half8*)&Bs[r][kb] = *(const half8*)(BT + (size_t)r * K + k0 + kb);
        }
        __syncthreads();
#pragma unroll
        for (int kc = 0; kc < 2; kc++) {
            half8 a = *(const half8*)&As[wave * 16 + l16][kc * 32 + quad * 8];
#pragma unroll
            for (int j = 0; j < 8; j++) {
                half8 bb = *(const half8*)&Bs[j * 16 + l16][kc * 32 + quad * 8];
                acc[j] = __builtin_amdgcn_mfma_f32_16x16x32_f16(a, bb, acc[j], 0, 0, 0);
            }
        }
        __syncthreads();
    }

    float gj[8], bj[8], biasj[8];
#pragma unroll
    for (int j = 0; j < 8; j++) {
        int col = j * 16 + l16;
        biasj[j] = bias[col];
        gj[j] = g[col];
        bj[j] = b[col];
    }
    int row0 = mBase + wave * 16 + quad * 4;
    float sum[4] = {}, sq[4] = {};
#pragma unroll
    for (int r = 0; r < 4; r++) {
        int row = row0 + r;
        bool ok = row < M;
        size_t base = (size_t)row * HDIM;
#pragma unroll
        for (int j = 0; j < 8; j++) {
            float v = acc[j][r] + biasj[j] + (ok ? (float)R16[base + j * 16 + l16] : 0.0f);
            acc[j][r] = v;
            sum[r] += v;
            sq[r] += v * v;
        }
    }
#pragma unroll
    for (int r = 0; r < 4; r++) {
#pragma unroll
        for (int off = 1; off < 16; off <<= 1) {
            sum[r] += __shfl_xor(sum[r], off);
            sq[r] += __shfl_xor(sq[r], off);
        }
    }
#pragma unroll
    for (int r = 0; r < 4; r++) {
        int row = row0 + r;
        if (row >= M) continue;
        size_t base = (size_t)row * HDIM;
        float mu = sum[r] * (1.0f / HDIM);
        float var = sq[r] * (1.0f / HDIM) - mu * mu;
        float invstd = rsqrtf(var + 1e-5f);
#pragma unroll
        for (int j = 0; j < 8; j++)
            C16[base + j * 16 + l16] = (_Float16)((acc[j][r] - mu) * invstd * gj[j] + bj[j]);
    }
}

// ---------------------------------------------------------------------------
// Fused FFN: LN(GELU(A@W1T + b1)@W2T + b2 + R16) * g + b.
// Output: C32 (final layer, f32) or C16 (f16).
// ---------------------------------------------------------------------------
__global__ __launch_bounds__(256) void ffn_fused(const _Float16* __restrict__ A,
                                                 const _Float16* __restrict__ W1T,
                                                 const float* __restrict__ b1,
                                                 const _Float16* __restrict__ W2T,
                                                 const float* __restrict__ b2,
                                                 const _Float16* __restrict__ R16,
                                                 const float* __restrict__ g,
                                                 const float* __restrict__ b,
                                                 float* __restrict__ C32,
                                                 _Float16* __restrict__ C16,
                                                 int M) {
    __shared__ _Float16 Ws[128][128 + 8];
    __shared__ _Float16 Mid[64][256 + 8];
    int tid = threadIdx.x;
    int wave = tid >> 6, lane = tid & 63;
    int quad = lane >> 4, l16 = lane & 15;
    int mBase = blockIdx.x * 64;

    half8 afrag[4];
    {
        int row = mBase + wave * 16 + l16;
#pragma unroll
        for (int kc = 0; kc < 4; kc++) {
            if (row < M)
                afrag[kc] = *(const half8*)(A + (size_t)row * HDIM + kc * 32 + quad * 8);
            else
                afrag[kc] = (half8)(_Float16)0.0f;
        }
    }

#pragma unroll
    for (int h = 0; h < 2; h++) {
        if (h) __syncthreads();
#pragma unroll
        for (int t = 0; t < 8; t++) {
            int idx = tid + t * 256;
            int r = idx >> 4, kb = (idx & 15) * 8;
            *(half8*)&Ws[r][kb] = *(const half8*)(W1T + (size_t)(h * 128 + r) * HDIM + kb);
        }
        __syncthreads();
        f32x4 acc[8] = {};
#pragma unroll
        for (int kc = 0; kc < 4; kc++) {
#pragma unroll
            for (int j = 0; j < 8; j++) {
                half8 bb = *(const half8*)&Ws[j * 16 + l16][kc * 32 + quad * 8];
                acc[j] = __builtin_amdgcn_mfma_f32_16x16x32_f16(afrag[kc], bb, acc[j], 0, 0, 0);
            }
        }
#pragma unroll
        for (int j = 0; j < 8; j++) {
            float bj1 = b1[h * 128 + j * 16 + l16];
#pragma unroll
            for (int r = 0; r < 4; r++) {
                float v = acc[j][r] + bj1;
                v = 0.5f * v * (1.0f + erff(v * 0.70710678118654752f));
                Mid[wave * 16 + quad * 4 + r][h * 128 + j * 16 + l16] = (_Float16)v;
            }
        }
    }
    __syncthreads();

    f32x4 acc2[8] = {};
#pragma unroll
    for (int kc2 = 0; kc2 < 2; kc2++) {
        if (kc2) __syncthreads();
#pragma unroll
        for (int t = 0; t < 8; t++) {
            int idx = tid + t * 256;
            int r = idx >> 4, kb = (idx & 15) * 8;
            *(half8*)&Ws[r][kb] = *(const half8*)(W2T + (size_t)r * FFH + kc2 * 128 + kb);
        }
        __syncthreads();
#pragma unroll
        for (int kc = 0; kc < 4; kc++) {
            half8 am = *(const half8*)&Mid[wave * 16 + l16][kc2 * 128 + kc * 32 + quad * 8];
#pragma unroll
            for (int j = 0; j < 8; j++) {
                half8 bb = *(const half8*)&Ws[j * 16 + l16][kc * 32 + quad * 8];
                acc2[j] = __builtin_amdgcn_mfma_f32_16x16x32_f16(am, bb, acc2[j], 0, 0, 0);
            }
        }
    }

    float gj[8], bj[8], b2j[8];
#pragma unroll
    for (int j = 0; j < 8; j++) {
        int col = j * 16 + l16;
        b2j[j] = b2[col];
        gj[j] = g[col];
        bj[j] = b[col];
    }
    int row0 = mBase + wave * 16 + quad * 4;
    float sum[4] = {}, sq[4] = {};
#pragma unroll
    for (int r = 0; r < 4; r++) {
        int row = row0 + r;
        bool ok = row < M;
        size_t base = (size_t)row * HDIM;
#pragma unroll
        for (int j = 0; j < 8; j++) {
            float v = acc2[j][r] + b2j[j] + (ok ? (float)R16[base + j * 16 + l16] : 0.0f);
            acc2[j][r] = v;
            sum[r] += v;
            sq[r] += v * v;
        }
    }
#pragma unroll
    for (int r = 0; r < 4; r++) {
#pragma unroll
        for (int off = 1; off < 16; off <<= 1) {
            sum[r] += __shfl_xor(sum[r], off);
            sq[r] += __shfl_xor(sq[r], off);
        }
    }
#pragma unroll
    for (int r = 0; r < 4; r++) {
        int row = row0 + r;
        if (row >= M) continue;
        size_t base = (size_t)row * HDIM;
        float mu = sum[r] * (1.0f / HDIM);
        float var = sq[r] * (1.0f / HDIM) - mu * mu;
        float invstd = rsqrtf(var + 1e-5f);
#pragma unroll
        for (int j = 0; j < 8; j++) {
            float o = (acc2[j][r] - mu) * invstd * gj[j] + bj[j];
            if (C32) C32[base + j * 16 + l16] = o;
            else     C16[base + j * 16 + l16] = (_Float16)o;
        }
    }
}

// ---------------------------------------------------------------------------
// GATv2 attention + aggregation, packed-f16 math, one wave per dst node,
// online softmax, 2-edge unroll. XLR: [n][1024] f16 (XL 0..511, XR 512..1023).
// Concat: f16 into XR half. Non-concat: head-mean + bias + f16-residual + LN
// fused, f16 out.
// ---------------------------------------------------------------------------
__global__ __launch_bounds__(256) void gat_edge_kernel(
    const _Float16* __restrict__ XLR,
    const int* __restrict__ row_ptr, const Edge* __restrict__ csr,
    const float* __restrict__ We,    // [2,512]
    const float* __restrict__ attW,  // [512]
    const float* __restrict__ cbias, // [512] or [128]
    _Float16* __restrict__ OUT16,
    const _Float16* __restrict__ R16, const float* __restrict__ lng,
    const float* __restrict__ lnb, _Float16* __restrict__ OUT16h,
    int n, int concat) {
    int tid = threadIdx.x;
    int wave = tid >> 6, lane = tid & 63;
    int node = blockIdx.x * 4 + wave;
    if (node >= n) return;
    int c0 = lane * 8;

    h8 xr8 = *(const h8*)(XLR + (size_t)node * 1024 + 512 + c0);
    h8 w08, w18, att8;
#pragma unroll
    for (int k = 0; k < 8; k++) {
        w08[k] = (_Float16)We[c0 + k];
        w18[k] = (_Float16)We[HH + c0 + k];
        att8[k] = (_Float16)attW[c0 + k];
    }
    const _Float16 slope = (_Float16)NEG_SLOPE;

    h8 acc2 = (h8)(_Float16)0.0f;
    float m = -INFINITY, l = 0.0f;
    int beg = row_ptr[node], end = row_ptr[node + 1];
    int j = beg;
    for (; j + 1 < end; j += 2) {
        Edge e0 = csr[j], e1 = csr[j + 1];
        h8 x0 = *(const h8*)(XLR + (size_t)e0.src * 1024 + c0);
        h8 x1 = *(const h8*)(XLR + (size_t)e1.src * 1024 + c0);
        h8 v0 = x0 + (xr8 + w08 * e0.ea0 + w18 * e0.ea1);
        h8 v1 = x1 + (xr8 + w08 * e1.ea0 + w18 * e1.ea1);
        v0 = __builtin_elementwise_max(v0, v0 * slope);
        v1 = __builtin_elementwise_max(v1, v1 * slope);
        float p0 = hsum8(v0 * att8);
        float p1 = hsum8(v1 * att8);
        p0 += __shfl_xor(p0, 1); p1 += __shfl_xor(p1, 1);
        p0 += __shfl_xor(p0, 2); p1 += __shfl_xor(p1, 2);
        p0 += __shfl_xor(p0, 4); p1 += __shfl_xor(p1, 4);
        p0 += __shfl_xor(p0, 8); p1 += __shfl_xor(p1, 8);
        float mnew = fmaxf(m, fmaxf(p0, p1));
        float sc = __expf(m - mnew);
        float e0f = __expf(p0 - mnew);
        float e1f = __expf(p1 - mnew);
        l = l * sc + e0f + e1f;
        acc2 = acc2 * (_Float16)sc + x0 * (_Float16)e0f + x1 * (_Float16)e1f;
        m = mnew;
    }
    if (j < end) {
        Edge e0 = csr[j];
        h8 x0 = *(const h8*)(XLR + (size_t)e0.src * 1024 + c0);
        h8 v0 = x0 + (xr8 + w08 * e0.ea0 + w18 * e0.ea1);
        v0 = __builtin_elementwise_max(v0, v0 * slope);
        float p0 = hsum8(v0 * att8);
        p0 += __shfl_xor(p0, 1);
        p0 += __shfl_xor(p0, 2);
        p0 += __shfl_xor(p0, 4);
        p0 += __shfl_xor(p0, 8);
        float mnew = fmaxf(m, p0);
        float sc = __expf(m - mnew);
        float e0f = __expf(p0 - mnew);
        l = l * sc + e0f;
        acc2 = acc2 * (_Float16)sc + x0 * (_Float16)e0f;
        m = mnew;
    }
    float invf = 1.0f / (l + 1e-16f);
    if (concat) {
        h8 o = acc2 * (_Float16)invf;
#pragma unroll
        for (int k = 0; k < 8; k++) o[k] = o[k] + (_Float16)cbias[c0 + k];
        *(h8*)(OUT16 + (size_t)node * 1024 + c0) = o;
    } else {
        float o8[8];
#pragma unroll
        for (int k = 0; k < 8; k++) {
            float a = (float)acc2[k] * invf;
            a += __shfl_xor(a, 16);
            a += __shfl_xor(a, 32);
            o8[k] = a;
        }
        float v8[8];
        float sum = 0.0f, sq = 0.0f;
        if (lane < 16) {
#pragma unroll
            for (int k = 0; k < 8; k++) {
                float v = o8[k] * 0.25f + cbias[c0 + k] + (float)R16[(size_t)node * HDIM + c0 + k];
                v8[k] = v;
                sum += v;
                sq += v * v;
            }
        }
#pragma unroll
        for (int off = 1; off < 16; off <<= 1) {
            sum += __shfl_xor(sum, off);
            sq += __shfl_xor(sq, off);
        }
        if (lane < 16) {
            float mu = sum * (1.0f / HDIM);
            float var = sq * (1.0f / HDIM) - mu * mu;
            float invstd = rsqrtf(var + 1e-5f);
#pragma unroll
            for (int k = 0; k < 8; k++)
                OUT16h[(size_t)node * HDIM + c0 + k] =
                    (_Float16)((v8[k] - mu) * invstd * lng[c0 + k] + lnb[c0 + k]);
        }
    }
}

// ---------------------------------------------------------------------------
extern "C" void kernel_launch(void* const* d_in, const int* in_sizes, int n_in,
                              void* d_out, int out_size, void* d_ws, size_t ws_size,
                              hipStream_t stream) {
    const float* x        = (const float*)d_in[0];
    const int*   ei       = (const int*)d_in[1];
    const float* eattr    = (const float*)d_in[2];
    const float* emb_w    = (const float*)d_in[3];
    const float* emb_b    = (const float*)d_in[4];
    const float* lin_l    = (const float*)d_in[5];
    const float* lin_r    = (const float*)d_in[6];
    const float* lin_edge = (const float*)d_in[7];
    const float* attw     = (const float*)d_in[8];
    const float* cb01     = (const float*)d_in[9];
    const float* cb2      = (const float*)d_in[10];
    const float* proj_w   = (const float*)d_in[11];
    const float* proj_b   = (const float*)d_in[12];
    const float* n1g      = (const float*)d_in[13];
    const float* n1b      = (const float*)d_in[14];
    const float* n2g      = (const float*)d_in[15];
    const float* n2b      = (const float*)d_in[16];
    const float* fw1      = (const float*)d_in[17];
    const float* fb1      = (const float*)d_in[18];
    const float* fw2      = (const float*)d_in[19];
    const float* fb2      = (const float*)d_in[20];
    float* out = (float*)d_out;

    const int n = in_sizes[0] / IN_DIM;   // 20000
    const int E = in_sizes[2] / 2;        // 320000
    const int EP = E + n;
    const int numMT = (n + 63) / 64;

    size_t off = 0;
    auto alloc = [&](size_t bytes) {
        void* p = (char*)d_ws + off;
        off += (bytes + 255) & ~(size_t)255;
        return p;
    };
    float* degasum = (float*)alloc((size_t)3 * n * 4);  // deg[n] + asum[2n]
    float* deg     = degasum;
    float* asum    = degasum + n;
    int*   row_ptr = (int*)alloc((size_t)(n + 1) * 4);
    int*   cur     = (int*)alloc((size_t)n * 4);
    Edge*  csr     = (Edge*)alloc((size_t)EP * 8);
    _Float16* H0h  = (_Float16*)alloc((size_t)n * HDIM * 2);
    _Float16* H1h  = (_Float16*)alloc((size_t)n * HDIM * 2);
    _Float16* XLR  = (_Float16*)alloc((size_t)n * 1024 * 2);
    _Float16* xh   = (_Float16*)alloc((size_t)n * 64 * 2);
    _Float16* wt_emb  = (_Float16*)alloc((size_t)HDIM * 64 * 2);
    _Float16* wt_llr  = (_Float16*)alloc((size_t)3 * 1024 * HDIM * 2);
    _Float16* wt_proj = (_Float16*)alloc((size_t)2 * HDIM * HH * 2);
    _Float16* wt_f1   = (_Float16*)alloc((size_t)3 * FFH * HDIM * 2);
    _Float16* wt_f2   = (_Float16*)alloc((size_t)3 * HDIM * FFH * 2);
    (void)ws_size;

    // ---- input prep ----
    xpad_kernel<<<(n * 64 + 255) / 256, 256, 0, stream>>>(x, xh, n);
    WDescs ds;
    int di = 0;
    ds.d[di++] = {emb_w, wt_emb, IN_DIM, 6, 7};
    for (int i = 0; i < 3; i++) {
        ds.d[di++] = {lin_l + (size_t)i * HDIM * HH, wt_llr + (size_t)i * 1024 * HDIM, HDIM, 7, 9};
        ds.d[di++] = {lin_r + (size_t)i * HDIM * HH, wt_llr + (size_t)i * 1024 * HDIM + (size_t)512 * HDIM, HDIM, 7, 9};
    }
    for (int i = 0; i < 2; i++)
        ds.d[di++] = {proj_w + (size_t)i * HH * HDIM, wt_proj + (size_t)i * HDIM * HH, HH, 9, 7};
    for (int i = 0; i < 3; i++)
        ds.d[di++] = {fw1 + (size_t)i * HDIM * FFH, wt_f1 + (size_t)i * FFH * HDIM, HDIM, 7, 8};
    for (int i = 0; i < 3; i++)
        ds.d[di++] = {fw2 + (size_t)i * FFH * HDIM, wt_f2 + (size_t)i * HDIM * FFH, FFH, 8, 7};
    wconv_kernel<<<dim3(64, 15), 256, 0, stream>>>(ds);

    // ---- CSR build ----
    (void)hipMemsetAsync(degasum, 0, (size_t)3 * n * 4, stream);
    deg_kernel<<<(E + 255) / 256, 256, 0, stream>>>(ei, eattr, deg, asum, E);
    scan_kernel<<<1, 1024, 0, stream>>>(deg, row_ptr, cur, n);
    scatter_kernel<<<(EP + 255) / 256, 256, 0, stream>>>(ei, eattr, deg, asum, cur, csr, E, n);

    // ---- Embedding: H0h = xh @ wt_emb + emb_b (B-stationary, f16) ----
    gemm_bstat<64><<<dim3(1, numMT), 256, 0, stream>>>(
        xh, 64, wt_emb, emb_b, H0h, n, HDIM, numMT);

    // ---- 3 GATv2 + FFN layers (all-f16 inter-layer state) ----
    for (int i = 0; i < 3; i++) {
        int concat = (i < 2);
        // fused lin_l|lin_r: XLR[n][1024]
        gemm_bstat<128><<<dim3(8, 157), 256, 0, stream>>>(
            H0h, HDIM, wt_llr + (size_t)i * 1024 * HDIM, nullptr, XLR, n, 1024, numMT);
        // gat: concat -> f16 into XR half; non-concat -> fused mean+bias+res+LN
        gat_edge_kernel<<<(n + 3) / 4, 256, 0, stream>>>(
            XLR, row_ptr, csr,
            lin_edge + (size_t)i * 2 * HH, attw + (size_t)i * HH,
            concat ? (cb01 + (size_t)i * HH) : cb2,
            XLR + 512,
            H0h, n1g + (size_t)i * HDIM, n1b + (size_t)i * HDIM, H1h,
            n, concat);
        if (concat) {
            // H1h = LN(proj(gatout) + pb + H0h)
            gemm_ln<<<(n + 63) / 64, 256, 0, stream>>>(
                XLR + 512, 1024, wt_proj + (size_t)i * HDIM * HH,
                proj_b + (size_t)i * HDIM, H0h,
                n1g + (size_t)i * HDIM, n1b + (size_t)i * HDIM,
                H1h, n, HH);
        }
        // {out|H0h} = LN(GELU(H1h@W1+b1)@W2 + b2 + H1h)
        ffn_fused<<<(n + 63) / 64, 256, 0, stream>>>(
            H1h, wt_f1 + (size_t)i * FFH * HDIM, fb1 + (size_t)i * FFH,
            wt_f2 + (size_t)i * HDIM * FFH, fb2 + (size_t)i * HDIM, H1h,
            n2g + (size_t)i * HDIM, n2b + (size_t)i * HDIM,
            (i == 2) ? out : nullptr, (i == 2) ? nullptr : H0h, n);
    }
}